// Round 10
// baseline (162.019 us; speedup 1.0000x reference)
//
#include <hip/hip_runtime.h>
#include <hip/hip_bf16.h>

typedef __bf16 bf16;
typedef __bf16 bf16x2 __attribute__((ext_vector_type(2)));
typedef __bf16 bf16x4 __attribute__((ext_vector_type(4)));
typedef __bf16 bf16x8 __attribute__((ext_vector_type(8)));
typedef float  f32x4  __attribute__((ext_vector_type(4)));

#define MFMA16(a,b,c) __builtin_amdgcn_mfma_f32_16x16x32_bf16((a),(b),(c),0,0,0)

// Problem constants: B=32, C=E=512, H=W=32 -> S=1024, 8 heads x 64
constexpr int Cn = 512;
constexpr int Sn = 1024;

// ---------------------------------------------------------------------------
// K0: weights fp32 -> bf16, ALL FOUR in MFMA-A-fragment order:
//     WF[((m*32+gr)*16 + kc)*512 + l*8 + i] = W_m[gr*16+(l&15)][kc*32+(l>>4)*8+i]
//     m: 0=Wq 1=Wk 2=Wv 3=Wo. (unchanged from R8/R9)
// ---------------------------------------------------------------------------
__global__ __launch_bounds__(256) void k_cvt_w(const float* __restrict__ Wq,
                                               const float* __restrict__ Wk,
                                               const float* __restrict__ Wv,
                                               const float* __restrict__ Wo,
                                               bf16* __restrict__ Wb) {
    int tid = blockIdx.x * 256 + threadIdx.x;   // 512 blocks x 256
    int oidx = tid * 8;
    int m  = oidx >> 18;
    int r  = oidx & 262143;
    int gr = r >> 13;
    int kc = (r >> 9) & 15;
    int l  = (r >> 3) & 63;
    const float* s = (m == 0) ? Wq : (m == 1) ? Wk : (m == 2) ? Wv : Wo;
    const float* src = s + (gr * 16 + (l & 15)) * 512 + kc * 32 + (l >> 4) * 8;
    float4 u = ((const float4*)src)[0], v = ((const float4*)src)[1];
    bf16x8 o;
    o[0] = (bf16)u.x; o[1] = (bf16)u.y; o[2] = (bf16)u.z; o[3] = (bf16)u.w;
    o[4] = (bf16)v.x; o[5] = (bf16)v.y; o[6] = (bf16)v.z; o[7] = (bf16)v.w;
    *(bf16x8*)(Wb + oidx) = o;
}

// ---------------------------------------------------------------------------
// K1: fused transpose + QKV GEMM + phi + per-(sub,head) partial KV / ksum.
//     R10: s-sub = 32 (4 subs/block) -> LDS 77 KB -> 2 blocks/CU, 8 waves/SIMD
//     (__launch_bounds__(1024,8); VGPR must stay <= 64). The co-resident block
//     fills MFMA/LDS pipes while this block sits at barriers/stage.
// ---------------------------------------------------------------------------
__global__ __launch_bounds__(1024, 8) void k_qkv(const float* __restrict__ x,
                                                 const bf16* __restrict__ Wb,
                                                 bf16* __restrict__ phiQ,
                                                 bf16* __restrict__ kvP,
                                                 float* __restrict__ ksP) {
    int bid = blockIdx.x;            // b*8 + st8
    int st8 = bid & 7, b = bid >> 3;
    int t = threadIdx.x, lane = t & 63, w = t >> 6;   // w in 0..15
    int l15 = lane & 15, g = lane >> 4;
    int hq   = w >> 2;               // head-within-round (0..3)
    int quad = w & 3;                // d-quad within head

    __shared__ bf16 xT[32][524];     // 33.5 KB [s][c] (stride 524: conflict-free frag reads)
    __shared__ bf16 pk[4][64][40];   // 20.5 KB phi(K) [d][s<32], 4 heads/round
    __shared__ bf16 vv[4][64][40];   // 20.5 KB V      [e][s<32]
    __shared__ float ksl[512];       //  2.0 KB ksum accumulator [h*64+d]

    if (t < 512) ksl[t] = 0.f;

    int rp = t >> 2;                 // c-pair: rows 2rp, 2rp+1 (0..255)
    int s8 = (t & 3) * 8;            // 8-s chunk

#pragma unroll 1
    for (int sub = 0; sub < 4; ++sub) {
        int srow0 = st8 * 128 + sub * 32;
        // ---- stage: x fp32 [c][s] -> xT bf16 [s][c] ----
        {
            const float* xr = x + ((size_t)b * Cn + 2 * rp) * Sn + srow0 + s8;
            float4 f0[2], f1[2];
#pragma unroll
            for (int j = 0; j < 2; ++j) {
                f0[j] = ((const float4*)xr)[j];
                f1[j] = ((const float4*)(xr + Sn))[j];
            }
#pragma unroll
            for (int j = 0; j < 2; ++j) {
                const float* e0 = (const float*)&f0[j];
                const float* e1 = (const float*)&f1[j];
#pragma unroll
                for (int e = 0; e < 4; ++e) {
                    int s = s8 + j * 4 + e;
                    bf16x2 pr;
                    pr[0] = (bf16)e0[e];
                    pr[1] = (bf16)e1[e];
                    *(bf16x2*)&xT[s][2 * rp] = pr;
                }
            }
        }
        __syncthreads();             // BAR1: xT ready (also fences ksl init)

#pragma unroll 1
        for (int rnd = 0; rnd < 2; ++rnd) {
            int h = rnd * 4 + hq;
            int gr = h * 4 + quad;   // 16-row group index (0..31)
            // ---- QKV compute: M=16 rows (h,quad), N=32, full k=512 ----
            f32x4 aQ[2], aK[2], aV[2];
#pragma unroll
            for (int n = 0; n < 2; ++n) {
                aQ[n] = (f32x4){0.f,0.f,0.f,0.f};
                aK[n] = (f32x4){0.f,0.f,0.f,0.f};
                aV[n] = (f32x4){0.f,0.f,0.f,0.f};
            }
            const bf16* wfQ = Wb + ((size_t)gr * 16) * 512 + lane * 8;
            const bf16* wfK = wfQ + (size_t)32 * 16 * 512;
            const bf16* wfV = wfQ + (size_t)64 * 16 * 512;
#pragma unroll 2
            for (int kc = 0; kc < 16; ++kc) {
                bf16x8 fq = *(const bf16x8*)(wfQ + kc * 512);
                bf16x8 fk = *(const bf16x8*)(wfK + kc * 512);
                bf16x8 fv = *(const bf16x8*)(wfV + kc * 512);
#pragma unroll
                for (int n = 0; n < 2; ++n) {
                    bf16x8 bf_ = *(const bf16x8*)&xT[n * 16 + l15][kc * 32 + g * 8];
                    aQ[n] = MFMA16(fq, bf_, aQ[n]);
                    aK[n] = MFMA16(fk, bf_, aK[n]);
                    aV[n] = MFMA16(fv, bf_, aV[n]);
                }
            }
            // ---- phi; pk/vv LDS writes; phiQ direct global; ksum ----
            float kspart[4] = {0.f, 0.f, 0.f, 0.f};
#pragma unroll
            for (int n = 0; n < 2; ++n) {
                bf16x4 qv;
#pragma unroll
                for (int r = 0; r < 4; ++r) {
                    float kv_ = aK[n][r];
                    kv_ = kv_ > 0.f ? kv_ + 1.f : __expf(kv_);
                    bf16 kb = (bf16)kv_;
                    kspart[r] += (float)kb;
                    pk[hq][quad * 16 + g * 4 + r][n * 16 + l15] = kb;
                    vv[hq][quad * 16 + g * 4 + r][n * 16 + l15] = (bf16)aV[n][r];
                    float q = aQ[n][r];
                    q = q > 0.f ? q + 1.f : __expf(q);
                    qv[r] = (bf16)q;
                }
                *(bf16x4*)(phiQ + ((size_t)b * Sn + srow0 + n * 16 + l15) * Cn
                           + h * 64 + quad * 16 + g * 4) = qv;
            }
#pragma unroll
            for (int r = 0; r < 4; ++r) {
                float v = kspart[r];
                v += __shfl_xor(v, 1);
                v += __shfl_xor(v, 2);
                v += __shfl_xor(v, 4);
                v += __shfl_xor(v, 8);
                if (l15 == 0) ksl[h * 64 + quad * 16 + g * 4 + r] += v;
            }
            __syncthreads();         // BAR2: pk/vv of this round ready
            // ---- KV partial MFMA: k = 32 s -> ONE k-step, 4 e-tiles ----
            f32x4 kvacc[4];
#pragma unroll
            for (int n = 0; n < 4; ++n) kvacc[n] = (f32x4){0.f,0.f,0.f,0.f};
            {
                bf16x8 af = *(const bf16x8*)&pk[hq][quad * 16 + l15][g * 8];
#pragma unroll
                for (int n = 0; n < 4; ++n) {
                    bf16x8 bf_ = *(const bf16x8*)&vv[hq][n * 16 + l15][g * 8];
                    kvacc[n] = MFMA16(af, bf_, kvacc[n]);
                }
            }
            // lane-packed coalesced store (k_red un-permutes):
            // value (n,r) of slot (quad*64+lane) = KV[d=quad*16+g*4+r][e=n*16+l15]
            {
                bf16x8 p0, p1;
#pragma unroll
                for (int r = 0; r < 4; ++r) {
                    p0[r]     = (bf16)kvacc[0][r];
                    p0[4 + r] = (bf16)kvacc[1][r];
                    p1[r]     = (bf16)kvacc[2][r];
                    p1[4 + r] = (bf16)kvacc[3][r];
                }
                size_t base = ((size_t)((b * 8 + h) * 32 + st8 * 4 + sub)) * 4096;
                bf16* dst = kvP + base + (size_t)(quad * 64 + lane) * 16;
                *(bf16x8*)(dst)     = p0;
                *(bf16x8*)(dst + 8) = p1;
            }
            __syncthreads();         // BAR3: KV reads done before next round's writes
        }
    }
    // epilogue: partial ksum -> ksP
    if (t < 512) {
        int h = t >> 6, d = t & 63;
        ksP[((b * 8 + h) * 8 + st8) * 64 + d] = ksl[t];
    }
}

// ---------------------------------------------------------------------------
// K2: reduce lane-packed partials (now 32 per bh) -> KVT[bh][e][d] bf16,
//     ksum[bh][d] fp32.
// ---------------------------------------------------------------------------
__global__ __launch_bounds__(256) void k_red(const bf16* __restrict__ kvP,
                                             const float* __restrict__ ksP,
                                             bf16* __restrict__ KVT,
                                             float* __restrict__ ksum) {
    int bh = blockIdx.x;
    int t = threadIdx.x;             // slot
    int wq = t >> 6, lane = t & 63, g = lane >> 4, l15 = lane & 15;
    float acc[16];
#pragma unroll
    for (int i = 0; i < 16; ++i) acc[i] = 0.f;
#pragma unroll 4
    for (int p = 0; p < 32; ++p) {
        const bf16* src = kvP + ((size_t)bh * 32 + p) * 4096 + (size_t)t * 16;
        bf16x8 v0 = *(const bf16x8*)(src);
        bf16x8 v1 = *(const bf16x8*)(src + 8);
#pragma unroll
        for (int i = 0; i < 8; ++i) { acc[i] += (float)v0[i]; acc[8 + i] += (float)v1[i]; }
    }
#pragma unroll
    for (int n = 0; n < 4; ++n) {
        bf16x4 o;
#pragma unroll
        for (int r = 0; r < 4; ++r) o[r] = (bf16)acc[n * 4 + r];
        *(bf16x4*)(KVT + (size_t)bh * 4096 + (n * 16 + l15) * 64 + wq * 16 + g * 4) = o;
    }
    if (t < 64) {
        float s = 0.f;
#pragma unroll
        for (int p = 0; p < 8; ++p) s += ksP[((size_t)bh * 8 + p) * 64 + t];
        ksum[bh * 64 + t] = s;
    }
}

// ---------------------------------------------------------------------------
// K3: apply + output GEMM (unchanged from R8).
// ---------------------------------------------------------------------------
__global__ __launch_bounds__(1024, 4) void k_apply(const bf16* __restrict__ phiQ,
                                                   const bf16* __restrict__ Wb,
                                                   const bf16* __restrict__ KVT,
                                                   const float* __restrict__ ksum,
                                                   const float* __restrict__ bo,
                                                   float* __restrict__ out) {
    int bid = blockIdx.x;            // b*8 + st8
    int st8 = bid & 7, b = bid >> 3;
    int t = threadIdx.x, lane = t & 63, w = t >> 6, l15 = lane & 15, g = lane >> 4;

    __shared__ bf16 pq[64][520];     // 66.5 KB phiQ tile, then O tile
    __shared__ float ksl[512];       //  2 KB
    __shared__ float rden[64][8];    //  2 KB
    __shared__ float bol[512];       //  2 KB

    if (t < 512) {
        ksl[t] = ksum[b * 512 + t];
        bol[t] = bo[t];
    }

#pragma unroll 1
    for (int sub = 0; sub < 2; ++sub) {
        int srow0 = st8 * 128 + sub * 64;
        // ---- stage phiQ tile [64 s][512 c] (coalesced 64B/thread) ----
        {
            int sr = t >> 4, c0 = (t & 15) * 32;
            const bf16* src = phiQ + ((size_t)b * Sn + srow0 + sr) * Cn + c0;
#pragma unroll
            for (int j = 0; j < 4; ++j)
                *(bf16x8*)&pq[sr][c0 + j * 8] = *(const bf16x8*)(src + j * 8);
        }
        __syncthreads();             // BAR1: pq + (ksl,bol on first sub) ready
        // ---- denominators: 512 (s,h) jobs, 2 threads each (32-elem halves) ----
        {
            int j = t >> 1, half = t & 1;
            int s = j & 63, h = j >> 6;
            float acc = 0.f;
#pragma unroll
            for (int dt = 0; dt < 4; ++dt) {
                bf16x8 v = *(const bf16x8*)&pq[s][h * 64 + half * 32 + dt * 8];
#pragma unroll
                for (int i = 0; i < 8; ++i)
                    acc += ksl[h * 64 + half * 32 + dt * 8 + i] * (float)v[i];
            }
            acc += __shfl_xor(acc, 1);
            if (half == 0) rden[s][h] = 1.f / (acc + 1e-6f);
        }
        __syncthreads();             // BAR2: rden ready (pq still phiQ)
        // ---- numerator: wave = (h = w>>1, ehalf = w&1): m = 32 e-rows ----
        int h = w >> 1, eh = w & 1;
        f32x4 accN[2][4];
#pragma unroll
        for (int mi = 0; mi < 2; ++mi)
#pragma unroll
            for (int n = 0; n < 4; ++n) accN[mi][n] = (f32x4){0.f,0.f,0.f,0.f};
        {
            const bf16* kvb = KVT + ((size_t)(b * 8 + h)) * 4096;
#pragma unroll
            for (int k2 = 0; k2 < 2; ++k2) {
#pragma unroll
                for (int mi = 0; mi < 2; ++mi) {
                    bf16x8 af = *(const bf16x8*)(kvb + (eh * 32 + mi * 16 + l15) * 64 + k2 * 32 + g * 8);
#pragma unroll
                    for (int n = 0; n < 4; ++n) {
                        bf16x8 bf_ = *(const bf16x8*)&pq[n * 16 + l15][h * 64 + k2 * 32 + g * 8];
                        accN[mi][n] = MFMA16(af, bf_, accN[mi][n]);
                    }
                }
            }
        }
        __syncthreads();             // BAR3: all numerator reads of pq done
        // ---- O = num * rden overwrites pq (cols h*64+eh*32 .. +32) ----
#pragma unroll
        for (int mi = 0; mi < 2; ++mi)
#pragma unroll
            for (int n = 0; n < 4; ++n) {
                float rd = rden[n * 16 + l15][h];
                bf16x4 ov;
#pragma unroll
                for (int r = 0; r < 4; ++r) ov[r] = (bf16)(accN[mi][n][r] * rd);
                *(bf16x4*)&pq[n * 16 + l15][h * 64 + eh * 32 + mi * 16 + g * 4] = ov;
            }
        __syncthreads();             // BAR4: O tile complete
        // ---- out = Wo @ O^T + bo: wave w owns rows m0..m0+31 ----
        int m0 = w * 32;
        f32x4 acc[2][4];
#pragma unroll
        for (int mi = 0; mi < 2; ++mi)
#pragma unroll
            for (int n = 0; n < 4; ++n) acc[mi][n] = (f32x4){0.f,0.f,0.f,0.f};
        const bf16* WoF = Wb + 786432 + (size_t)(w * 2) * 16 * 512 + lane * 8;
#pragma unroll 2
        for (int kc = 0; kc < 16; ++kc) {
            bf16x8 fa0 = *(const bf16x8*)(WoF + kc * 512);
            bf16x8 fa1 = *(const bf16x8*)(WoF + (16 + kc) * 512);
#pragma unroll
            for (int n = 0; n < 4; ++n) {
                bf16x8 bf_ = *(const bf16x8*)&pq[n * 16 + l15][kc * 32 + g * 8];
                acc[0][n] = MFMA16(fa0, bf_, acc[0][n]);
                acc[1][n] = MFMA16(fa1, bf_, acc[1][n]);
            }
        }
#pragma unroll
        for (int mi = 0; mi < 2; ++mi)
#pragma unroll
            for (int r = 0; r < 4; ++r) {
                int co = m0 + mi * 16 + g * 4 + r;
                float bb = bol[co];
#pragma unroll
                for (int n = 0; n < 4; ++n)
                    out[((size_t)b * Cn + co) * Sn + srow0 + n * 16 + l15] = acc[mi][n][r] + bb;
            }
        __syncthreads();             // BAR5: pq reads done before next sub stage
    }
}

// ---------------------------------------------------------------------------
extern "C" void kernel_launch(void* const* d_in, const int* in_sizes, int n_in,
                              void* d_out, int out_size, void* d_ws, size_t ws_size,
                              hipStream_t stream) {
    const float* x  = (const float*)d_in[0];
    const float* Wq = (const float*)d_in[1];
    const float* Wk = (const float*)d_in[2];
    const float* Wv = (const float*)d_in[3];
    const float* Wo = (const float*)d_in[4];
    const float* bo = (const float*)d_in[5];
    float* out = (float*)d_out;

    char* ws = (char*)d_ws;
    bf16*  phiQ = (bf16*)ws;                       // 33,554,432 B
    bf16*  Wb   = (bf16*)(ws + 33554432);          //  2,097,152 B
    float* ksP  = (float*)(ws + 35651584);         //    524,288 B
    bf16*  KVT  = (bf16*)(ws + 36175872);          //  2,097,152 B
    float* ks   = (float*)(ws + 38273024);         //     65,536 B   (total 38.3 MB)

    // KV partials (32 per bh, 64 MiB) alias d_out (exactly 64 MiB): fully
    // written by k_qkv, consumed by k_red, then k_apply overwrites everything.
    bf16*  kvP  = (bf16*)d_out;

    k_cvt_w <<< 512,  256, 0, stream>>>(Wq, Wk, Wv, Wo, Wb);
    k_qkv   <<< 256, 1024, 0, stream>>>(x, Wb, phiQ, kvP, ksP);
    k_red   <<< 256,  256, 0, stream>>>(kvP, ksP, KVT, ks);
    k_apply <<< 256, 1024, 0, stream>>>(phiQ, Wb, KVT, ks, bo, out);
}

// Round 11
// 115.981 us; speedup vs baseline: 1.3969x; 1.3969x over previous
//
#include <hip/hip_runtime.h>
#include <hip/hip_bf16.h>

typedef __bf16 bf16;
typedef __bf16 bf16x2 __attribute__((ext_vector_type(2)));
typedef __bf16 bf16x4 __attribute__((ext_vector_type(4)));
typedef __bf16 bf16x8 __attribute__((ext_vector_type(8)));
typedef float  f32x4  __attribute__((ext_vector_type(4)));

#define MFMA16(a,b,c) __builtin_amdgcn_mfma_f32_16x16x32_bf16((a),(b),(c),0,0,0)

// Problem constants: B=32, C=E=512, H=W=32 -> S=1024, 8 heads x 64
constexpr int Cn = 512;
constexpr int Sn = 1024;

// LDS-only barrier: make LDS writes visible, but do NOT drain outstanding
// global stores (phiQ/kvP are consumed only by later kernels).
__device__ __forceinline__ void bar_lds() {
    asm volatile("s_waitcnt lgkmcnt(0)" ::: "memory");
    __builtin_amdgcn_sched_barrier(0);
    __builtin_amdgcn_s_barrier();
}

// ---------------------------------------------------------------------------
// K0: weights fp32 -> bf16, ALL FOUR in MFMA-A-fragment order:
//     WF[((m*32+gr)*16 + kc)*512 + l*8 + i] = W_m[gr*16+(l&15)][kc*32+(l>>4)*8+i]
//     m: 0=Wq 1=Wk 2=Wv 3=Wo. (unchanged)
// ---------------------------------------------------------------------------
__global__ __launch_bounds__(256) void k_cvt_w(const float* __restrict__ Wq,
                                               const float* __restrict__ Wk,
                                               const float* __restrict__ Wv,
                                               const float* __restrict__ Wo,
                                               bf16* __restrict__ Wb) {
    int tid = blockIdx.x * 256 + threadIdx.x;   // 512 blocks x 256
    int oidx = tid * 8;
    int m  = oidx >> 18;
    int r  = oidx & 262143;
    int gr = r >> 13;
    int kc = (r >> 9) & 15;
    int l  = (r >> 3) & 63;
    const float* s = (m == 0) ? Wq : (m == 1) ? Wk : (m == 2) ? Wv : Wo;
    const float* src = s + (gr * 16 + (l & 15)) * 512 + kc * 32 + (l >> 4) * 8;
    float4 u = ((const float4*)src)[0], v = ((const float4*)src)[1];
    bf16x8 o;
    o[0] = (bf16)u.x; o[1] = (bf16)u.y; o[2] = (bf16)u.z; o[3] = (bf16)u.w;
    o[4] = (bf16)v.x; o[5] = (bf16)v.y; o[6] = (bf16)v.z; o[7] = (bf16)v.w;
    *(bf16x8*)(Wb + oidx) = o;
}

// ---------------------------------------------------------------------------
// K1: fused transpose + QKV GEMM + phi + per-(sub,head) partial KV / ksum.
//     R11 = R8 structure (s-sub 64, 2 subs, grid 256 x 1024 thr) +
//       (a) T14 async stage: sub1's x-loads issued in the prologue, LDS write
//           deferred to after sub0/rnd1's BAR2 (xT provably dead there);
//       (b) lgkm-only barriers: global stores stay in flight across BAR2/BAR3.
// ---------------------------------------------------------------------------
__global__ __launch_bounds__(1024, 4) void k_qkv(const float* __restrict__ x,
                                                 const bf16* __restrict__ Wb,
                                                 bf16* __restrict__ phiQ,
                                                 bf16* __restrict__ kvP,
                                                 float* __restrict__ ksP) {
    int bid = blockIdx.x;            // b*8 + st8
    int st8 = bid & 7, b = bid >> 3;
    int t = threadIdx.x, lane = t & 63, w = t >> 6;   // w in 0..15
    int l15 = lane & 15, g = lane >> 4;
    int hq   = w >> 2;               // head-within-round (0..3)
    int quad = w & 3;                // d-quad within head

    __shared__ bf16 xT[64][520];     // 66.5 KB [s][c] full-k tile
    __shared__ bf16 pk[4][64][72];   // 36.9 KB phi(K) [d][s], 4 heads/round
    __shared__ bf16 vv[4][64][72];   // 36.9 KB V      [e][s]
    __shared__ float ksl[512];       //  2.0 KB ksum accumulator [h*64+d]

    if (t < 512) ksl[t] = 0.f;

    int rp = t >> 2;                 // c-pair: rows 2rp, 2rp+1
    int sq = (t & 3) << 4;           // 16-s chunk base

    // ---- prologue: stage sub0, issue sub1 loads (kept in regs) ----
    const float* xr0 = x + ((size_t)b * Cn + 2 * rp) * Sn + st8 * 128 + sq;
    {
        float4 f0[4], f1[4];
#pragma unroll
        for (int j = 0; j < 4; ++j) {
            f0[j] = ((const float4*)xr0)[j];
            f1[j] = ((const float4*)(xr0 + Sn))[j];
        }
#pragma unroll
        for (int j = 0; j < 4; ++j) {
            const float* e0 = (const float*)&f0[j];
            const float* e1 = (const float*)&f1[j];
#pragma unroll
            for (int e = 0; e < 4; ++e) {
                bf16x2 pr; pr[0] = (bf16)e0[e]; pr[1] = (bf16)e1[e];
                *(bf16x2*)&xT[sq + j * 4 + e][2 * rp] = pr;
            }
        }
    }
    float4 fB0[4], fB1[4];           // sub1 x data, in flight through sub0
#pragma unroll
    for (int j = 0; j < 4; ++j) {
        fB0[j] = ((const float4*)(xr0 + 64))[j];
        fB1[j] = ((const float4*)(xr0 + 64 + Sn))[j];
    }
    __syncthreads();                 // BAR1: xT(sub0) ready

#pragma unroll 1
    for (int sub = 0; sub < 2; ++sub) {
        int srow0 = st8 * 128 + sub * 64;
#pragma unroll 1
        for (int rnd = 0; rnd < 2; ++rnd) {
            int h = rnd * 4 + hq;
            int gr = h * 4 + quad;   // 16-row group index (0..31)
            // ---- QKV compute: M=16 rows (h,quad), N=64, full k=512 ----
            f32x4 aQ[4], aK[4], aV[4];
#pragma unroll
            for (int n = 0; n < 4; ++n) {
                aQ[n] = (f32x4){0.f,0.f,0.f,0.f};
                aK[n] = (f32x4){0.f,0.f,0.f,0.f};
                aV[n] = (f32x4){0.f,0.f,0.f,0.f};
            }
            const bf16* wfQ = Wb + ((size_t)gr * 16) * 512 + lane * 8;
            const bf16* wfK = wfQ + (size_t)32 * 16 * 512;
            const bf16* wfV = wfQ + (size_t)64 * 16 * 512;
#pragma unroll 2
            for (int kc = 0; kc < 16; ++kc) {
                bf16x8 fq = *(const bf16x8*)(wfQ + kc * 512);
                bf16x8 fk = *(const bf16x8*)(wfK + kc * 512);
                bf16x8 fv = *(const bf16x8*)(wfV + kc * 512);
#pragma unroll
                for (int n = 0; n < 4; ++n) {
                    bf16x8 bf_ = *(const bf16x8*)&xT[n * 16 + l15][kc * 32 + g * 8];
                    aQ[n] = MFMA16(fq, bf_, aQ[n]);
                    aK[n] = MFMA16(fk, bf_, aK[n]);
                    aV[n] = MFMA16(fv, bf_, aV[n]);
                }
            }
            // ---- phi; pk/vv LDS writes; phiQ direct global; ksum ----
            float kspart[4] = {0.f, 0.f, 0.f, 0.f};
#pragma unroll
            for (int n = 0; n < 4; ++n) {
                bf16x4 qv;
#pragma unroll
                for (int r = 0; r < 4; ++r) {
                    float kv_ = aK[n][r];
                    kv_ = kv_ > 0.f ? kv_ + 1.f : __expf(kv_);
                    bf16 kb = (bf16)kv_;
                    kspart[r] += (float)kb;
                    pk[hq][quad * 16 + g * 4 + r][n * 16 + l15] = kb;
                    vv[hq][quad * 16 + g * 4 + r][n * 16 + l15] = (bf16)aV[n][r];
                    float q = aQ[n][r];
                    q = q > 0.f ? q + 1.f : __expf(q);
                    qv[r] = (bf16)q;
                }
                *(bf16x4*)(phiQ + ((size_t)b * Sn + srow0 + n * 16 + l15) * Cn
                           + h * 64 + quad * 16 + g * 4) = qv;
            }
#pragma unroll
            for (int r = 0; r < 4; ++r) {
                float v = kspart[r];
                v += __shfl_xor(v, 1);
                v += __shfl_xor(v, 2);
                v += __shfl_xor(v, 4);
                v += __shfl_xor(v, 8);
                if (l15 == 0) ksl[h * 64 + quad * 16 + g * 4 + r] += v;
            }
            bar_lds();               // BAR2: pk/vv visible; QKV xT reads done
            // ---- deferred stage write: xT dead after sub0/rnd1's QKV ----
            if (sub == 0 && rnd == 1) {
#pragma unroll
                for (int j = 0; j < 4; ++j) {
                    const float* e0 = (const float*)&fB0[j];
                    const float* e1 = (const float*)&fB1[j];
#pragma unroll
                    for (int e = 0; e < 4; ++e) {
                        bf16x2 pr; pr[0] = (bf16)e0[e]; pr[1] = (bf16)e1[e];
                        *(bf16x2*)&xT[sq + j * 4 + e][2 * rp] = pr;
                    }
                }
            }
            // ---- KV partial MFMA: all 16 waves, m = quad of head h ----
            f32x4 kvacc[4];
#pragma unroll
            for (int n = 0; n < 4; ++n) kvacc[n] = (f32x4){0.f,0.f,0.f,0.f};
#pragma unroll
            for (int k2 = 0; k2 < 2; ++k2) {
                bf16x8 af = *(const bf16x8*)&pk[hq][quad * 16 + l15][k2 * 32 + g * 8];
#pragma unroll
                for (int n = 0; n < 4; ++n) {
                    bf16x8 bf_ = *(const bf16x8*)&vv[hq][n * 16 + l15][k2 * 32 + g * 8];
                    kvacc[n] = MFMA16(af, bf_, kvacc[n]);
                }
            }
            // lane-packed coalesced store (k_red un-permutes):
            // value (n,r) of slot (quad*64+lane) = KV[d=quad*16+g*4+r][e=n*16+l15]
            {
                bf16x8 p0, p1;
#pragma unroll
                for (int r = 0; r < 4; ++r) {
                    p0[r]     = (bf16)kvacc[0][r];
                    p0[4 + r] = (bf16)kvacc[1][r];
                    p1[r]     = (bf16)kvacc[2][r];
                    p1[4 + r] = (bf16)kvacc[3][r];
                }
                size_t base = ((size_t)((b * 8 + h) * 16 + st8 * 2 + sub)) * 4096;
                bf16* dst = kvP + base + (size_t)(quad * 64 + lane) * 16;
                *(bf16x8*)(dst)     = p0;
                *(bf16x8*)(dst + 8) = p1;
            }
            bar_lds();               // BAR3: pk/vv free; xT(sub1) visible
        }
    }
    // epilogue: partial ksum -> ksP (synced by final BAR3)
    if (t < 512) {
        int h = t >> 6, d = t & 63;
        ksP[((b * 8 + h) * 8 + st8) * 64 + d] = ksl[t];
    }
}

// ---------------------------------------------------------------------------
// K2: reduce lane-packed partials (16 per bh) -> KVT[bh][e][d] bf16,
//     ksum[bh][d] fp32. (R8/R9 version)
// ---------------------------------------------------------------------------
__global__ __launch_bounds__(256) void k_red(const bf16* __restrict__ kvP,
                                             const float* __restrict__ ksP,
                                             bf16* __restrict__ KVT,
                                             float* __restrict__ ksum) {
    int bh = blockIdx.x;
    int t = threadIdx.x;             // slot
    int wq = t >> 6, lane = t & 63, g = lane >> 4, l15 = lane & 15;
    float acc[16];
#pragma unroll
    for (int i = 0; i < 16; ++i) acc[i] = 0.f;
#pragma unroll
    for (int p = 0; p < 16; ++p) {
        const bf16* src = kvP + ((size_t)bh * 16 + p) * 4096 + (size_t)t * 16;
        bf16x8 v0 = *(const bf16x8*)(src);
        bf16x8 v1 = *(const bf16x8*)(src + 8);
#pragma unroll
        for (int i = 0; i < 8; ++i) { acc[i] += (float)v0[i]; acc[8 + i] += (float)v1[i]; }
    }
#pragma unroll
    for (int n = 0; n < 4; ++n) {
        bf16x4 o;
#pragma unroll
        for (int r = 0; r < 4; ++r) o[r] = (bf16)acc[n * 4 + r];
        *(bf16x4*)(KVT + (size_t)bh * 4096 + (n * 16 + l15) * 64 + wq * 16 + g * 4) = o;
    }
    if (t < 64) {
        float s = 0.f;
#pragma unroll
        for (int p = 0; p < 8; ++p) s += ksP[((size_t)bh * 8 + p) * 64 + t];
        ksum[bh * 64 + t] = s;
    }
}

// ---------------------------------------------------------------------------
// K3: apply + output GEMM (unchanged from R8).
// ---------------------------------------------------------------------------
__global__ __launch_bounds__(1024, 4) void k_apply(const bf16* __restrict__ phiQ,
                                                   const bf16* __restrict__ Wb,
                                                   const bf16* __restrict__ KVT,
                                                   const float* __restrict__ ksum,
                                                   const float* __restrict__ bo,
                                                   float* __restrict__ out) {
    int bid = blockIdx.x;            // b*8 + st8
    int st8 = bid & 7, b = bid >> 3;
    int t = threadIdx.x, lane = t & 63, w = t >> 6, l15 = lane & 15, g = lane >> 4;

    __shared__ bf16 pq[64][520];     // 66.5 KB phiQ tile, then O tile
    __shared__ float ksl[512];       //  2 KB
    __shared__ float rden[64][8];    //  2 KB
    __shared__ float bol[512];       //  2 KB

    if (t < 512) {
        ksl[t] = ksum[b * 512 + t];
        bol[t] = bo[t];
    }

#pragma unroll 1
    for (int sub = 0; sub < 2; ++sub) {
        int srow0 = st8 * 128 + sub * 64;
        // ---- stage phiQ tile [64 s][512 c] (coalesced 64B/thread) ----
        {
            int sr = t >> 4, c0 = (t & 15) * 32;
            const bf16* src = phiQ + ((size_t)b * Sn + srow0 + sr) * Cn + c0;
#pragma unroll
            for (int j = 0; j < 4; ++j)
                *(bf16x8*)&pq[sr][c0 + j * 8] = *(const bf16x8*)(src + j * 8);
        }
        __syncthreads();             // BAR1: pq + (ksl,bol on first sub) ready
        // ---- denominators: 512 (s,h) jobs, 2 threads each (32-elem halves) ----
        {
            int j = t >> 1, half = t & 1;
            int s = j & 63, h = j >> 6;
            float acc = 0.f;
#pragma unroll
            for (int dt = 0; dt < 4; ++dt) {
                bf16x8 v = *(const bf16x8*)&pq[s][h * 64 + half * 32 + dt * 8];
#pragma unroll
                for (int i = 0; i < 8; ++i)
                    acc += ksl[h * 64 + half * 32 + dt * 8 + i] * (float)v[i];
            }
            acc += __shfl_xor(acc, 1);
            if (half == 0) rden[s][h] = 1.f / (acc + 1e-6f);
        }
        __syncthreads();             // BAR2: rden ready (pq still phiQ)
        // ---- numerator: wave = (h = w>>1, ehalf = w&1): m = 32 e-rows ----
        int h = w >> 1, eh = w & 1;
        f32x4 accN[2][4];
#pragma unroll
        for (int mi = 0; mi < 2; ++mi)
#pragma unroll
            for (int n = 0; n < 4; ++n) accN[mi][n] = (f32x4){0.f,0.f,0.f,0.f};
        {
            const bf16* kvb = KVT + ((size_t)(b * 8 + h)) * 4096;
#pragma unroll
            for (int k2 = 0; k2 < 2; ++k2) {
#pragma unroll
                for (int mi = 0; mi < 2; ++mi) {
                    bf16x8 af = *(const bf16x8*)(kvb + (eh * 32 + mi * 16 + l15) * 64 + k2 * 32 + g * 8);
#pragma unroll
                    for (int n = 0; n < 4; ++n) {
                        bf16x8 bf_ = *(const bf16x8*)&pq[n * 16 + l15][h * 64 + k2 * 32 + g * 8];
                        accN[mi][n] = MFMA16(af, bf_, accN[mi][n]);
                    }
                }
            }
        }
        __syncthreads();             // BAR3: all numerator reads of pq done
        // ---- O = num * rden overwrites pq (cols h*64+eh*32 .. +32) ----
#pragma unroll
        for (int mi = 0; mi < 2; ++mi)
#pragma unroll
            for (int n = 0; n < 4; ++n) {
                float rd = rden[n * 16 + l15][h];
                bf16x4 ov;
#pragma unroll
                for (int r = 0; r < 4; ++r) ov[r] = (bf16)(accN[mi][n][r] * rd);
                *(bf16x4*)&pq[n * 16 + l15][h * 64 + eh * 32 + mi * 16 + g * 4] = ov;
            }
        __syncthreads();             // BAR4: O tile complete
        // ---- out = Wo @ O^T + bo: wave w owns rows m0..m0+31 ----
        int m0 = w * 32;
        f32x4 acc[2][4];
#pragma unroll
        for (int mi = 0; mi < 2; ++mi)
#pragma unroll
            for (int n = 0; n < 4; ++n) acc[mi][n] = (f32x4){0.f,0.f,0.f,0.f};
        const bf16* WoF = Wb + 786432 + (size_t)(w * 2) * 16 * 512 + lane * 8;
#pragma unroll 2
        for (int kc = 0; kc < 16; ++kc) {
            bf16x8 fa0 = *(const bf16x8*)(WoF + kc * 512);
            bf16x8 fa1 = *(const bf16x8*)(WoF + (16 + kc) * 512);
#pragma unroll
            for (int n = 0; n < 4; ++n) {
                bf16x8 bf_ = *(const bf16x8*)&pq[n * 16 + l15][kc * 32 + g * 8];
                acc[0][n] = MFMA16(fa0, bf_, acc[0][n]);
                acc[1][n] = MFMA16(fa1, bf_, acc[1][n]);
            }
        }
#pragma unroll
        for (int mi = 0; mi < 2; ++mi)
#pragma unroll
            for (int r = 0; r < 4; ++r) {
                int co = m0 + mi * 16 + g * 4 + r;
                float bb = bol[co];
#pragma unroll
                for (int n = 0; n < 4; ++n)
                    out[((size_t)b * Cn + co) * Sn + srow0 + n * 16 + l15] = acc[mi][n][r] + bb;
            }
        __syncthreads();             // BAR5: pq reads done before next sub stage
    }
}

// ---------------------------------------------------------------------------
extern "C" void kernel_launch(void* const* d_in, const int* in_sizes, int n_in,
                              void* d_out, int out_size, void* d_ws, size_t ws_size,
                              hipStream_t stream) {
    const float* x  = (const float*)d_in[0];
    const float* Wq = (const float*)d_in[1];
    const float* Wk = (const float*)d_in[2];
    const float* Wv = (const float*)d_in[3];
    const float* Wo = (const float*)d_in[4];
    const float* bo = (const float*)d_in[5];
    float* out = (float*)d_out;

    char* ws = (char*)d_ws;
    bf16*  phiQ = (bf16*)ws;                       // 33,554,432 B
    bf16*  Wb   = (bf16*)(ws + 33554432);          //  2,097,152 B
    float* ksP  = (float*)(ws + 35651584);         //    524,288 B
    bf16*  KVT  = (bf16*)(ws + 36175872);          //  2,097,152 B
    float* ks   = (float*)(ws + 38273024);         //     65,536 B   (total 38.3 MB)

    // KV partials (16 per bh, 32 MiB) alias d_out: fully written by k_qkv,
    // consumed by k_red, then k_apply overwrites the whole output buffer.
    bf16*  kvP  = (bf16*)d_out;

    k_cvt_w <<< 512,  256, 0, stream>>>(Wq, Wk, Wv, Wo, Wb);
    k_qkv   <<< 256, 1024, 0, stream>>>(x, Wb, phiQ, kvP, ksP);
    k_red   <<< 256,  256, 0, stream>>>(kvP, ksP, KVT, ks);
    k_apply <<< 256, 1024, 0, stream>>>(phiQ, Wb, KVT, ks, bo, out);
}